// Round 1
// baseline (257.813 us; speedup 1.0000x reference)
//
#include <hip/hip_runtime.h>

// Problem constants (match reference)
#define B_      16
#define L_      4096
#define D_      256
#define K2_     512     // 2*D
#define TILE_M  64      // rows per workgroup tile
#define BK      64      // K-step
#define KITERS  8       // K2_/BK
#define PSTRIDE 264     // floats per (b,tile) partial record: [m, sA, sO[256], pad]

typedef float f32x4 __attribute__((ext_vector_type(4)));
typedef short bf16x8 __attribute__((ext_vector_type(8)));

__device__ __forceinline__ unsigned short f2bf(float x) {
    unsigned int u = __float_as_uint(x);
    u += 0x7FFF + ((u >> 16) & 1);      // round-to-nearest-even
    return (unsigned short)(u >> 16);
}

__device__ __forceinline__ void gload_lds16(const void* g, void* l) {
    __builtin_amdgcn_global_load_lds(
        (const __attribute__((address_space(1))) unsigned int*)g,
        (__attribute__((address_space(3))) unsigned int*)l, 16, 0, 0);
}

// ---------------------------------------------------------------------------
// prep: convert W_hist -> bf16, pre-swizzled per k-tile LDS image in ws;
//       compute aeff[b][d] = (a[d] + 0.5*q[b][d]) / 16
// ---------------------------------------------------------------------------
__global__ __launch_bounds__(256) void prep_kernel(
    const float* __restrict__ Wh, const float* __restrict__ protos,
    const float* __restrict__ q, const int* __restrict__ pidx,
    unsigned short* __restrict__ wsW, float* __restrict__ aeff)
{
    const int blk = blockIdx.x, tid = threadIdx.x;
    if (blk < 256) {
        // one bf16-pair (2 consecutive e) per thread; 65536 pairs total
        int p  = blk * 256 + tid;
        int d  = p >> 8;          // W row (output dim), 256 pairs per row
        int pe = p & 255;
        int e  = pe * 2;
        int t  = e >> 6;          // k-tile index
        int kk = e & 63;          // k within tile (even)
        float2 w = *reinterpret_cast<const float2*>(Wh + d * K2_ + e);
        unsigned int v = (unsigned int)f2bf(w.x) | ((unsigned int)f2bf(w.y) << 16);
        int dst = t * 32768 + ((d * 128 + kk * 2) ^ ((d & 7) << 4));
        *reinterpret_cast<unsigned int*>(reinterpret_cast<char*>(wsW) + dst) = v;
    } else {
        int b = blk - 256;
        int d = tid;
        int pi = pidx[0];
        aeff[b * D_ + d] = (protos[pi * D_ + d] + 0.5f * q[b * D_ + d]) * 0.0625f;
    }
}

// ---------------------------------------------------------------------------
// main: per (b, row-tile) fused GEMM + tanh + logits + tile-local softmax
// 256 threads = 4 waves; wave w owns output cols [w*64, w*64+64)
// ---------------------------------------------------------------------------
__global__ __launch_bounds__(256, 2) void main_kernel(
    const float* __restrict__ h, const float* __restrict__ rp, const float* __restrict__ rn,
    const int* __restrict__ lengths, const unsigned short* __restrict__ wsW,
    const float* __restrict__ aeff, const float* __restrict__ bhist,
    float* __restrict__ partials)
{
    const int bid = blockIdx.x;
    const int b   = bid >> 6;
    const int t   = bid & 63;
    const int len = lengths[b];
    const int l0  = t * TILE_M;
    if (l0 >= len) return;          // fully masked tile: no work

    __shared__ __align__(16) unsigned short Albs[TILE_M * BK];   // 8 KB, swizzled
    __shared__ __align__(16) unsigned short Blbs[D_ * BK];       // 32 KB, swizzled
    __shared__ float red[4 * TILE_M];                            // per-wave logit partials
    __shared__ float pbuf[TILE_M];                               // tile softmax weights

    const int tid  = threadIdx.x;
    const int lane = tid & 63;
    const int wv   = tid >> 6;
    const int r16  = lane & 15;
    const int kg   = lane >> 4;

    // A-staging mapping: thread -> (row, 16 contiguous k)
    const int ar  = tid >> 2;
    const int akk = (tid & 3) * 16;

    const f32x4 zero4 = {0.f, 0.f, 0.f, 0.f};
    f32x4 acc[4][4];
#pragma unroll
    for (int m = 0; m < 4; ++m)
#pragma unroll
        for (int n = 0; n < 4; ++n) acc[m][n] = zero4;

    char* Ab = reinterpret_cast<char*>(Albs);
    char* Bb = reinterpret_cast<char*>(Blbs);

    for (int tk = 0; tk < KITERS; ++tk) {
        // ---- stage B: pre-swizzled bf16 W tile, linear global_load_lds ----
        const char* bsrc = reinterpret_cast<const char*>(wsW) + tk * 32768;
#pragma unroll
        for (int i = 0; i < 8; ++i) {
            int off = i * 4096 + wv * 1024;
            gload_lds16(bsrc + off + lane * 16, Bb + off);
        }
        // ---- stage A: f32 load -> bf16 -> swizzled ds_write_b128 ----
        {
            float vals[16];
            if (tk < 4) {
                const float* src = h + ((size_t)(b * L_ + l0 + ar)) * D_ + tk * 64 + akk;
#pragma unroll
                for (int i = 0; i < 4; ++i) {
                    float4 v = reinterpret_cast<const float4*>(src)[i];
                    vals[i*4+0] = v.x; vals[i*4+1] = v.y; vals[i*4+2] = v.z; vals[i*4+3] = v.w;
                }
            } else {
                size_t o0 = ((size_t)(b * L_ + l0 + ar)) * D_ + (tk - 4) * 64 + akk;
                const float* sp = rp + o0;
                const float* sn = rn + o0;
#pragma unroll
                for (int i = 0; i < 4; ++i) {
                    float4 vp = reinterpret_cast<const float4*>(sp)[i];
                    float4 vn = reinterpret_cast<const float4*>(sn)[i];
                    vals[i*4+0] = vp.x - vn.x; vals[i*4+1] = vp.y - vn.y;
                    vals[i*4+2] = vp.z - vn.z; vals[i*4+3] = vp.w - vn.w;
                }
            }
            unsigned int pk[8];
#pragma unroll
            for (int i = 0; i < 8; ++i)
                pk[i] = (unsigned int)f2bf(vals[2*i]) | ((unsigned int)f2bf(vals[2*i+1]) << 16);
            int s0 = (ar * 128 + akk * 2) ^ ((ar & 7) << 4);
            int s1 = (ar * 128 + akk * 2 + 16) ^ ((ar & 7) << 4);
            *reinterpret_cast<uint4*>(Ab + s0) = make_uint4(pk[0], pk[1], pk[2], pk[3]);
            *reinterpret_cast<uint4*>(Ab + s1) = make_uint4(pk[4], pk[5], pk[6], pk[7]);
        }
        __syncthreads();   // compiler drains vmcnt+lgkmcnt before s_barrier

        // ---- compute: 16 ds_read_b128 + 32 MFMA ----
#pragma unroll
        for (int ks = 0; ks < 2; ++ks) {
            const int kk = ks * 32 + kg * 8;
            bf16x8 af[4], bf[4];
#pragma unroll
            for (int m = 0; m < 4; ++m) {
                int row = m * 16 + r16;
                int off = (row * 128 + kk * 2) ^ ((row & 7) << 4);
                af[m] = *reinterpret_cast<const bf16x8*>(Ab + off);
            }
#pragma unroll
            for (int n = 0; n < 4; ++n) {
                int d = wv * 64 + n * 16 + r16;
                int off = (d * 128 + kk * 2) ^ ((d & 7) << 4);
                bf[n] = *reinterpret_cast<const bf16x8*>(Bb + off);
            }
#pragma unroll
            for (int m = 0; m < 4; ++m)
#pragma unroll
                for (int n = 0; n < 4; ++n)
                    acc[m][n] = __builtin_amdgcn_mfma_f32_16x16x32_bf16(af[m], bf[n], acc[m][n], 0, 0, 0);
        }
        __syncthreads();
    }

    // ---- epilogue: o = tanh(pre+bias); logits; tile-local online softmax ----
    float av[4], bh[4];
#pragma unroll
    for (int n = 0; n < 4; ++n) {
        int col = wv * 64 + n * 16 + r16;
        av[n] = aeff[b * D_ + col];
        bh[n] = bhist[col];
    }
    float part[4][4];
#pragma unroll
    for (int m = 0; m < 4; ++m)
#pragma unroll
        for (int rg = 0; rg < 4; ++rg) part[m][rg] = 0.f;
#pragma unroll
    for (int m = 0; m < 4; ++m)
#pragma unroll
        for (int n = 0; n < 4; ++n)
#pragma unroll
            for (int rg = 0; rg < 4; ++rg) {
                float o = tanhf(acc[m][n][rg] + bh[n]);
                acc[m][n][rg] = o;                 // keep o in-register
                part[m][rg] += o * av[n];
            }
    // reduce logit partials across the 16-lane col groups
#pragma unroll
    for (int off = 1; off < 16; off <<= 1)
#pragma unroll
        for (int m = 0; m < 4; ++m)
#pragma unroll
            for (int rg = 0; rg < 4; ++rg)
                part[m][rg] += __shfl_xor(part[m][rg], off, 64);
    if (r16 == 0) {
#pragma unroll
        for (int m = 0; m < 4; ++m)
#pragma unroll
            for (int rg = 0; rg < 4; ++rg)
                red[wv * 64 + m * 16 + kg * 4 + rg] = part[m][rg];
    }
    __syncthreads();

    float* pout = partials + (size_t)(b * 64 + t) * PSTRIDE;
    if (tid < 64) {
        int row = tid;
        float lg = red[row] + red[64 + row] + red[128 + row] + red[192 + row];
        bool valid = (l0 + row) < len;
        float mv = valid ? lg : -3.0e38f;
#pragma unroll
        for (int off = 1; off < 64; off <<= 1)
            mv = fmaxf(mv, __shfl_xor(mv, off, 64));
        float p = valid ? __expf(lg - mv) : 0.f;
        float sa = p;
#pragma unroll
        for (int off = 1; off < 64; off <<= 1)
            sa += __shfl_xor(sa, off, 64);
        pbuf[row] = p;
        if (tid == 0) { pout[0] = mv; pout[1] = sa; }
    }
    __syncthreads();

    // s_o[col] = sum_rows p[row] * o[row, col]
    float so[4] = {0.f, 0.f, 0.f, 0.f};
#pragma unroll
    for (int m = 0; m < 4; ++m)
#pragma unroll
        for (int rg = 0; rg < 4; ++rg) {
            float p = pbuf[m * 16 + kg * 4 + rg];
#pragma unroll
            for (int n = 0; n < 4; ++n)
                so[n] += p * acc[m][n][rg];
        }
#pragma unroll
    for (int n = 0; n < 4; ++n) {
        so[n] += __shfl_xor(so[n], 16, 64);
        so[n] += __shfl_xor(so[n], 32, 64);
    }
    if (lane < 16) {
#pragma unroll
        for (int n = 0; n < 4; ++n)
            pout[2 + wv * 64 + n * 16 + lane] = so[n];
    }
}

// ---------------------------------------------------------------------------
// reduce: per batch combine tile partials -> s_q; z; delta; softplus; mean
// ---------------------------------------------------------------------------
__global__ __launch_bounds__(256) void reduce_kernel(
    const float* __restrict__ partials, const int* __restrict__ lengths,
    const float* __restrict__ protos, const int* __restrict__ pidx,
    const float* __restrict__ q,
    const float* __restrict__ Wq_w, const float* __restrict__ Wq_b,
    const float* __restrict__ Ws_w, const float* __restrict__ Ws_b,
    const float* __restrict__ rpos, const float* __restrict__ rneg,
    float* __restrict__ out)
{
    const int b   = blockIdx.x;
    const int tid = threadIdx.x;
    const int len = lengths[b];
    const int nT  = (len + TILE_M - 1) / TILE_M;

    __shared__ __align__(16) float mArr[64];
    __shared__ __align__(16) float sAArr[64];
    __shared__ __align__(16) float sq[D_];
    __shared__ __align__(16) float qlds[D_];
    __shared__ float wsum[4];

    const float* pbase = partials + (size_t)b * 64 * PSTRIDE;
    if (tid < nT) {
        mArr[tid]  = pbase[(size_t)tid * PSTRIDE];
        sAArr[tid] = pbase[(size_t)tid * PSTRIDE + 1];
    }
    qlds[tid] = q[b * D_ + tid];
    __syncthreads();

    float M = -3.0e38f;
    for (int t = 0; t < nT; ++t) M = fmaxf(M, mArr[t]);
    float den = 0.f, num = 0.f;
    for (int t = 0; t < nT; ++t) {
        float f = __expf(mArr[t] - M);
        den += f * sAArr[t];
        num += f * pbase[(size_t)t * PSTRIDE + 2 + tid];
    }
    sq[tid] = num / den;
    __syncthreads();

    const int pi = pidx[0];
    float zd = protos[pi * D_ + tid] + Wq_b[tid] + Ws_b[tid];
    const float4* wqr = reinterpret_cast<const float4*>(Wq_w + (size_t)tid * D_);
    const float4* wsr = reinterpret_cast<const float4*>(Ws_w + (size_t)tid * D_);
    const float4* q4  = reinterpret_cast<const float4*>(qlds);
    const float4* s4  = reinterpret_cast<const float4*>(sq);
    float accq = 0.f, accs = 0.f;
#pragma unroll 4
    for (int e = 0; e < D_ / 4; ++e) {
        float4 wq = wqr[e], ws = wsr[e], qv = q4[e], sv = s4[e];
        accq += wq.x * qv.x + wq.y * qv.y + wq.z * qv.z + wq.w * qv.w;
        accs += ws.x * sv.x + ws.y * sv.y + ws.z * sv.z + ws.w * sv.w;
    }
    zd += accq + accs;

    float v = zd * (rpos[b * D_ + tid] - rneg[b * D_ + tid]);
#pragma unroll
    for (int off = 1; off < 64; off <<= 1) v += __shfl_xor(v, off, 64);
    if ((tid & 63) == 0) wsum[tid >> 6] = v;
    __syncthreads();
    if (tid == 0) {
        float delta = wsum[0] + wsum[1] + wsum[2] + wsum[3];
        float x = -delta;
        float sp = fmaxf(x, 0.f) + log1pf(__expf(-fabsf(x)));
        atomicAdd(out, sp * (1.0f / (float)B_));
    }
}

// ---------------------------------------------------------------------------
extern "C" void kernel_launch(void* const* d_in, const int* in_sizes, int n_in,
                              void* d_out, int out_size, void* d_ws, size_t ws_size,
                              hipStream_t stream) {
    const float* q       = (const float*)d_in[0];
    const float* r_pos   = (const float*)d_in[1];
    const float* r_neg   = (const float*)d_in[2];
    const float* h       = (const float*)d_in[3];
    const float* rp      = (const float*)d_in[4];
    const float* rn      = (const float*)d_in[5];
    const int*   lengths = (const int*)d_in[6];
    const int*   pidx    = (const int*)d_in[7];
    const float* protos  = (const float*)d_in[8];
    const float* Wh_w    = (const float*)d_in[9];
    const float* Wh_b    = (const float*)d_in[10];
    const float* Wq_w    = (const float*)d_in[11];
    const float* Wq_b    = (const float*)d_in[12];
    const float* Ws_w    = (const float*)d_in[13];
    const float* Ws_b    = (const float*)d_in[14];
    float* out = (float*)d_out;

    char* ws = (char*)d_ws;
    unsigned short* wsW = (unsigned short*)ws;          // 256 KB pre-swizzled bf16 W
    float* aeff     = (float*)(ws + 262144);            // 16 KB
    float* partials = (float*)(ws + 278528);            // 16*64*264*4 ~= 1.03 MB

    hipMemsetAsync(out, 0, sizeof(float), stream);
    prep_kernel<<<dim3(272), dim3(256), 0, stream>>>(Wh_w, protos, q, pidx, wsW, aeff);
    main_kernel<<<dim3(B_ * 64), dim3(256), 0, stream>>>(h, rp, rn, lengths, wsW, aeff, Wh_b, partials);
    reduce_kernel<<<dim3(B_), dim3(256), 0, stream>>>(partials, lengths, protos, pidx, q,
                                                      Wq_w, Wq_b, Ws_w, Ws_b, r_pos, r_neg, out);
}

// Round 2
// 253.344 us; speedup vs baseline: 1.0176x; 1.0176x over previous
//
#include <hip/hip_runtime.h>

// Problem constants (match reference)
#define B_      16
#define L_      4096
#define D_      256
#define K2_     512     // 2*D
#define TILE_M  64      // rows per workgroup tile
#define BK      64      // K-step
#define KITERS  8       // K2_/BK
#define PSTRIDE 264     // floats per (b,tile) partial record: [m, sA, sO[256], pad]

typedef float f32x4 __attribute__((ext_vector_type(4)));
typedef short bf16x8 __attribute__((ext_vector_type(8)));

__device__ __forceinline__ unsigned short f2bf(float x) {
    unsigned int u = __float_as_uint(x);
    u += 0x7FFF + ((u >> 16) & 1);      // round-to-nearest-even
    return (unsigned short)(u >> 16);
}

__device__ __forceinline__ void gload_lds16(const void* g, void* l) {
    __builtin_amdgcn_global_load_lds(
        (const __attribute__((address_space(1))) unsigned int*)g,
        (__attribute__((address_space(3))) unsigned int*)l, 16, 0, 0);
}

__device__ __forceinline__ float fast_tanh(float x) {
    // 1 - 2/(e^{2x}+1); e=inf -> 1, e=0 -> -1 (graceful at extremes)
    float e = __expf(2.0f * x);
    return 1.0f - __fdividef(2.0f, e + 1.0f);
}

// ---------------------------------------------------------------------------
// prep: convert W_hist -> bf16, pre-swizzled per k-tile LDS image in ws;
//       compute aeff[b][d] = (a[d] + 0.5*q[b][d]) / 16
// ---------------------------------------------------------------------------
__global__ __launch_bounds__(256) void prep_kernel(
    const float* __restrict__ Wh, const float* __restrict__ protos,
    const float* __restrict__ q, const int* __restrict__ pidx,
    unsigned short* __restrict__ wsW, float* __restrict__ aeff)
{
    const int blk = blockIdx.x, tid = threadIdx.x;
    if (blk < 256) {
        int d  = blk;               // W row (output dim)
        int e  = tid * 2;           // element pair
        int t  = e >> 6;            // k-tile index
        int kk = e & 63;            // k within tile (even)
        float2 w = *reinterpret_cast<const float2*>(Wh + d * K2_ + e);
        unsigned int v = (unsigned int)f2bf(w.x) | ((unsigned int)f2bf(w.y) << 16);
        int dst = t * 32768 + ((d * 128 + kk * 2) ^ ((d & 7) << 4));
        *reinterpret_cast<unsigned int*>(reinterpret_cast<char*>(wsW) + dst) = v;
    } else {
        int b = blk - 256;
        int d = tid;
        int pi = pidx[0];
        aeff[b * D_ + d] = (protos[pi * D_ + d] + 0.5f * q[b * D_ + d]) * 0.0625f;
    }
}

// ---------------------------------------------------------------------------
// main: per (b, row-tile) fused GEMM + tanh + logits + tile-local softmax
// 256 threads = 4 waves; wave w owns output cols [w*64, w*64+64)
// Double-buffered LDS (A 2x8KB + B 2x32KB = 80KB), 1 barrier per K-iter.
// ---------------------------------------------------------------------------
__global__ __launch_bounds__(256, 2) void main_kernel(
    const float* __restrict__ h, const float* __restrict__ rp, const float* __restrict__ rn,
    const int* __restrict__ lengths, const unsigned short* __restrict__ wsW,
    const float* __restrict__ aeff, const float* __restrict__ bhist,
    float* __restrict__ partials)
{
    const int bid = blockIdx.x;
    const int b   = bid >> 6;
    const int t   = bid & 63;
    const int len = lengths[b];
    const int l0  = t * TILE_M;
    if (l0 >= len) return;          // fully masked tile: no work

    __shared__ __align__(16) char SM[81920];     // [A0 8K][A1 8K][B0 32K][B1 32K]

    const int tid  = threadIdx.x;
    const int lane = tid & 63;
    const int wv   = tid >> 6;
    const int r16  = lane & 15;
    const int kg   = lane >> 4;

    // A-staging mapping: thread -> (row, 16 contiguous k)
    const int ar  = tid >> 2;
    const int akk = (tid & 3) * 16;
    const int s0  = (ar * 128 + akk * 2) ^ ((ar & 7) << 4);
    const int s1  = (ar * 128 + akk * 2 + 16) ^ ((ar & 7) << 4);

    const f32x4 zero4 = {0.f, 0.f, 0.f, 0.f};
    f32x4 acc[4][4];
#pragma unroll
    for (int m = 0; m < 4; ++m)
#pragma unroll
        for (int n = 0; n < 4; ++n) acc[m][n] = zero4;

    f32x4 ra[4], rb[4];   // A prefetch registers (raw f32)

    // ---- helpers -----------------------------------------------------------
    auto stageB = [&](int buf, int tk) {
        const char* bsrc = reinterpret_cast<const char*>(wsW) + tk * 32768;
        char* dst = SM + 16384 + buf * 32768;
#pragma unroll
        for (int i = 0; i < 8; ++i) {
            int off = i * 4096 + wv * 1024;
            gload_lds16(bsrc + off + lane * 16, dst + off);
        }
    };
    auto loadA = [&](int tk) {
        if (tk < 4) {
            const float* src = h + ((size_t)(b * L_ + l0 + ar)) * D_ + tk * 64 + akk;
#pragma unroll
            for (int i = 0; i < 4; ++i) ra[i] = reinterpret_cast<const f32x4*>(src)[i];
        } else {
            size_t o0 = ((size_t)(b * L_ + l0 + ar)) * D_ + (tk - 4) * 64 + akk;
#pragma unroll
            for (int i = 0; i < 4; ++i) ra[i] = reinterpret_cast<const f32x4*>(rp + o0)[i];
#pragma unroll
            for (int i = 0; i < 4; ++i) rb[i] = reinterpret_cast<const f32x4*>(rn + o0)[i];
        }
    };
    auto writeA = [&](int buf, int tk) {
        float vals[16];
        if (tk < 4) {
#pragma unroll
            for (int i = 0; i < 4; ++i)
#pragma unroll
                for (int j = 0; j < 4; ++j) vals[i * 4 + j] = ra[i][j];
        } else {
#pragma unroll
            for (int i = 0; i < 4; ++i)
#pragma unroll
                for (int j = 0; j < 4; ++j) vals[i * 4 + j] = ra[i][j] - rb[i][j];
        }
        unsigned int pk[8];
#pragma unroll
        for (int i = 0; i < 8; ++i)
            pk[i] = (unsigned int)f2bf(vals[2 * i]) | ((unsigned int)f2bf(vals[2 * i + 1]) << 16);
        char* Ab = SM + buf * 8192;
        *reinterpret_cast<uint4*>(Ab + s0) = make_uint4(pk[0], pk[1], pk[2], pk[3]);
        *reinterpret_cast<uint4*>(Ab + s1) = make_uint4(pk[4], pk[5], pk[6], pk[7]);
    };
    auto computeT = [&](int buf) {
        const char* Ab = SM + buf * 8192;
        const char* Bb = SM + 16384 + buf * 32768;
#pragma unroll
        for (int ks = 0; ks < 2; ++ks) {
            const int kk = ks * 32 + kg * 8;
            bf16x8 af[4], bf[4];
#pragma unroll
            for (int m = 0; m < 4; ++m) {
                int row = m * 16 + r16;
                int off = (row * 128 + kk * 2) ^ ((row & 7) << 4);
                af[m] = *reinterpret_cast<const bf16x8*>(Ab + off);
            }
#pragma unroll
            for (int n = 0; n < 4; ++n) {
                int d = wv * 64 + n * 16 + r16;
                int off = (d * 128 + kk * 2) ^ ((d & 7) << 4);
                bf[n] = *reinterpret_cast<const bf16x8*>(Bb + off);
            }
#pragma unroll
            for (int m = 0; m < 4; ++m)
#pragma unroll
                for (int n = 0; n < 4; ++n)
                    acc[m][n] = __builtin_amdgcn_mfma_f32_16x16x32_bf16(af[m], bf[n], acc[m][n], 0, 0, 0);
        }
    };

    // ---- pipelined K-loop: stage(k+1) issued before compute(k) -------------
    loadA(0);
    stageB(0, 0);
    writeA(0, 0);
    __syncthreads();

    int buf = 0;
    for (int tk = 0; tk < KITERS; ++tk) {
        const bool pf = (tk + 1) < KITERS;
        if (pf) { stageB(buf ^ 1, tk + 1); loadA(tk + 1); }
        computeT(buf);
        if (pf) writeA(buf ^ 1, tk + 1);   // vmcnt wait for loadA lands here (post-compute)
        __syncthreads();
        buf ^= 1;
    }

    // ---- epilogue: o = tanh(pre+bias); logits; tile-local softmax ----------
    float* red  = reinterpret_cast<float*>(SM);        // overlay on dead A buffers
    float* pbuf = reinterpret_cast<float*>(SM + 1024);

    float av[4], bh[4];
#pragma unroll
    for (int n = 0; n < 4; ++n) {
        int col = wv * 64 + n * 16 + r16;
        av[n] = aeff[b * D_ + col];
        bh[n] = bhist[col];
    }
    float part[4][4];
#pragma unroll
    for (int m = 0; m < 4; ++m)
#pragma unroll
        for (int rg = 0; rg < 4; ++rg) part[m][rg] = 0.f;
#pragma unroll
    for (int m = 0; m < 4; ++m)
#pragma unroll
        for (int n = 0; n < 4; ++n)
#pragma unroll
            for (int rg = 0; rg < 4; ++rg) {
                float o = fast_tanh(acc[m][n][rg] + bh[n]);
                acc[m][n][rg] = o;                 // keep o in-register
                part[m][rg] += o * av[n];
            }
    // reduce logit partials across the 16-lane col groups
#pragma unroll
    for (int off = 1; off < 16; off <<= 1)
#pragma unroll
        for (int m = 0; m < 4; ++m)
#pragma unroll
            for (int rg = 0; rg < 4; ++rg)
                part[m][rg] += __shfl_xor(part[m][rg], off, 64);
    if (r16 == 0) {
#pragma unroll
        for (int m = 0; m < 4; ++m)
#pragma unroll
            for (int rg = 0; rg < 4; ++rg)
                red[wv * 64 + m * 16 + kg * 4 + rg] = part[m][rg];
    }
    __syncthreads();

    float* pout = partials + (size_t)(b * 64 + t) * PSTRIDE;
    if (tid < 64) {
        int row = tid;
        float lg = red[row] + red[64 + row] + red[128 + row] + red[192 + row];
        bool valid = (l0 + row) < len;
        float mv = valid ? lg : -3.0e38f;
#pragma unroll
        for (int off = 1; off < 64; off <<= 1)
            mv = fmaxf(mv, __shfl_xor(mv, off, 64));
        float p = valid ? __expf(lg - mv) : 0.f;
        float sa = p;
#pragma unroll
        for (int off = 1; off < 64; off <<= 1)
            sa += __shfl_xor(sa, off, 64);
        pbuf[row] = p;
        if (tid == 0) { pout[0] = mv; pout[1] = sa; }
    }
    __syncthreads();

    // s_o[col] = sum_rows p[row] * o[row, col]
    float so[4] = {0.f, 0.f, 0.f, 0.f};
#pragma unroll
    for (int m = 0; m < 4; ++m)
#pragma unroll
        for (int rg = 0; rg < 4; ++rg) {
            float p = pbuf[m * 16 + kg * 4 + rg];
#pragma unroll
            for (int n = 0; n < 4; ++n)
                so[n] += p * acc[m][n][rg];
        }
#pragma unroll
    for (int n = 0; n < 4; ++n) {
        so[n] += __shfl_xor(so[n], 16, 64);
        so[n] += __shfl_xor(so[n], 32, 64);
    }
    if (lane < 16) {
#pragma unroll
        for (int n = 0; n < 4; ++n)
            pout[2 + wv * 64 + n * 16 + lane] = so[n];
    }
}

// ---------------------------------------------------------------------------
// reduce: per batch combine tile partials -> s_q; z; delta; softplus; mean
// GEMV phase: 4 lanes cooperate per W-row (coalesced 64B/lane segments)
// ---------------------------------------------------------------------------
__global__ __launch_bounds__(256) void reduce_kernel(
    const float* __restrict__ partials, const int* __restrict__ lengths,
    const float* __restrict__ protos, const int* __restrict__ pidx,
    const float* __restrict__ q,
    const float* __restrict__ Wq_w, const float* __restrict__ Wq_b,
    const float* __restrict__ Ws_w, const float* __restrict__ Ws_b,
    const float* __restrict__ rpos, const float* __restrict__ rneg,
    float* __restrict__ out)
{
    const int b   = blockIdx.x;
    const int tid = threadIdx.x;
    const int lane = tid & 63;
    const int wv   = tid >> 6;
    const int len = lengths[b];
    const int nT  = (len + TILE_M - 1) / TILE_M;

    __shared__ __align__(16) float mArr[64];
    __shared__ __align__(16) float sAArr[64];
    __shared__ __align__(16) float sq[D_];
    __shared__ __align__(16) float qlds[D_];
    __shared__ __align__(16) float zbuf[D_];
    __shared__ float wsum[4];

    const float* pbase = partials + (size_t)b * 64 * PSTRIDE;
    if (tid < nT) {
        mArr[tid]  = pbase[(size_t)tid * PSTRIDE];
        sAArr[tid] = pbase[(size_t)tid * PSTRIDE + 1];
    }
    qlds[tid] = q[b * D_ + tid];
    __syncthreads();

    float M = -3.0e38f;
    for (int t = 0; t < nT; ++t) M = fmaxf(M, mArr[t]);
    float den = 0.f, num = 0.f;
    for (int t = 0; t < nT; ++t) {
        float f = __expf(mArr[t] - M);
        den += f * sAArr[t];
        num += f * pbase[(size_t)t * PSTRIDE + 2 + tid];
    }
    sq[tid] = num / den;
    __syncthreads();

    // z GEMV: 4 lanes per row, each lane covers 64 consecutive e
    const int c = lane & 3;
    const float4* q4 = reinterpret_cast<const float4*>(qlds) + c * 16;
    const float4* s4 = reinterpret_cast<const float4*>(sq) + c * 16;
#pragma unroll
    for (int p = 0; p < 4; ++p) {
        int drow = p * 64 + wv * 16 + (lane >> 2);
        const float4* wq4 = reinterpret_cast<const float4*>(Wq_w + (size_t)drow * D_) + c * 16;
        const float4* ws4 = reinterpret_cast<const float4*>(Ws_w + (size_t)drow * D_) + c * 16;
        float a = 0.f;
#pragma unroll 4
        for (int i = 0; i < 16; ++i) {
            float4 wq = wq4[i], ws = ws4[i], qv = q4[i], sv = s4[i];
            a += wq.x * qv.x + wq.y * qv.y + wq.z * qv.z + wq.w * qv.w;
            a += ws.x * sv.x + ws.y * sv.y + ws.z * sv.z + ws.w * sv.w;
        }
        a += __shfl_xor(a, 1, 64);
        a += __shfl_xor(a, 2, 64);
        if (c == 0) zbuf[drow] = a;
    }
    __syncthreads();

    const int pi = pidx[0];
    float zd = protos[pi * D_ + tid] + Wq_b[tid] + Ws_b[tid] + zbuf[tid];
    float v = zd * (rpos[b * D_ + tid] - rneg[b * D_ + tid]);
#pragma unroll
    for (int off = 1; off < 64; off <<= 1) v += __shfl_xor(v, off, 64);
    if (lane == 0) wsum[wv] = v;
    __syncthreads();
    if (tid == 0) {
        float delta = wsum[0] + wsum[1] + wsum[2] + wsum[3];
        float x = -delta;
        float sp = fmaxf(x, 0.f) + log1pf(__expf(-fabsf(x)));
        atomicAdd(out, sp * (1.0f / (float)B_));
    }
}

// ---------------------------------------------------------------------------
extern "C" void kernel_launch(void* const* d_in, const int* in_sizes, int n_in,
                              void* d_out, int out_size, void* d_ws, size_t ws_size,
                              hipStream_t stream) {
    const float* q       = (const float*)d_in[0];
    const float* r_pos   = (const float*)d_in[1];
    const float* r_neg   = (const float*)d_in[2];
    const float* h       = (const float*)d_in[3];
    const float* rp      = (const float*)d_in[4];
    const float* rn      = (const float*)d_in[5];
    const int*   lengths = (const int*)d_in[6];
    const int*   pidx    = (const int*)d_in[7];
    const float* protos  = (const float*)d_in[8];
    const float* Wh_w    = (const float*)d_in[9];
    const float* Wh_b    = (const float*)d_in[10];
    const float* Wq_w    = (const float*)d_in[11];
    const float* Wq_b    = (const float*)d_in[12];
    const float* Ws_w    = (const float*)d_in[13];
    const float* Ws_b    = (const float*)d_in[14];
    float* out = (float*)d_out;

    char* ws = (char*)d_ws;
    unsigned short* wsW = (unsigned short*)ws;          // 256 KB pre-swizzled bf16 W
    float* aeff     = (float*)(ws + 262144);            // 16 KB
    float* partials = (float*)(ws + 278528);            // 16*64*264*4 ~= 1.03 MB

    hipMemsetAsync(out, 0, sizeof(float), stream);
    prep_kernel<<<dim3(272), dim3(256), 0, stream>>>(Wh_w, protos, q, pidx, wsW, aeff);
    main_kernel<<<dim3(B_ * 64), dim3(256), 0, stream>>>(h, rp, rn, lengths, wsW, aeff, Wh_b, partials);
    reduce_kernel<<<dim3(B_), dim3(256), 0, stream>>>(partials, lengths, protos, pidx, q,
                                                      Wq_w, Wq_b, Ws_w, Ws_b, r_pos, r_neg, out);
}

// Round 4
// 244.977 us; speedup vs baseline: 1.0524x; 1.0342x over previous
//
#include <hip/hip_runtime.h>

// Problem constants (match reference)
#define B_      16
#define L_      4096
#define D_      256
#define K2_     512     // 2*D
#define TILE_M  64      // rows per workgroup tile
#define BK      64      // K-step
#define KITERS  8       // K2_/BK
#define PSTRIDE 264     // floats per (b,tile) partial record: [m, sA, sO[256], pad]

typedef float f32x4 __attribute__((ext_vector_type(4)));
typedef short bf16x8 __attribute__((ext_vector_type(8)));

__device__ __forceinline__ unsigned short f2bf(float x) {
    unsigned int u = __float_as_uint(x);
    u += 0x7FFF + ((u >> 16) & 1);      // round-to-nearest-even
    return (unsigned short)(u >> 16);
}
__device__ __forceinline__ unsigned int pk2(float a, float b) {
    return (unsigned int)f2bf(a) | ((unsigned int)f2bf(b) << 16);
}
__device__ __forceinline__ bf16x8 pack8(f32x4 a, f32x4 b) {
    union { bf16x8 v; unsigned int u[4]; } r;
    r.u[0] = pk2(a[0], a[1]); r.u[1] = pk2(a[2], a[3]);
    r.u[2] = pk2(b[0], b[1]); r.u[3] = pk2(b[2], b[3]);
    return r.v;
}
__device__ __forceinline__ void gload_lds16(const void* g, void* l) {
    __builtin_amdgcn_global_load_lds(
        (const __attribute__((address_space(1))) unsigned int*)g,
        (__attribute__((address_space(3))) unsigned int*)l, 16, 0, 0);
}
__device__ __forceinline__ float fast_tanh(float x) {
    float e = __expf(2.0f * x);
    return 1.0f - __fdividef(2.0f, e + 1.0f);
}

// ---------------------------------------------------------------------------
// prep: blk<256: W_hist -> bf16 pre-swizzled tiles; blk 256..271: aeff;
//       blk 272: compacted valid-tile table
// ---------------------------------------------------------------------------
__global__ __launch_bounds__(256) void prep_kernel(
    const float* __restrict__ Wh, const float* __restrict__ protos,
    const float* __restrict__ q, const int* __restrict__ pidx,
    const int* __restrict__ lengths,
    unsigned short* __restrict__ wsW, float* __restrict__ aeff,
    int* __restrict__ tiles, int* __restrict__ tileCnt)
{
    const int blk = blockIdx.x, tid = threadIdx.x;
    if (blk < 256) {
        int d  = blk;               // W row (output dim)
        int e  = tid * 2;           // element pair
        int t  = e >> 6;            // k-tile index
        int kk = e & 63;            // k within tile (even)
        float2 w = *reinterpret_cast<const float2*>(Wh + d * K2_ + e);
        unsigned int v = pk2(w.x, w.y);
        int dst = t * 32768 + ((d * 128 + kk * 2) ^ ((d & 7) << 4));
        *reinterpret_cast<unsigned int*>(reinterpret_cast<char*>(wsW) + dst) = v;
    } else if (blk < 272) {
        int b = blk - 256;
        int d = tid;
        int pi = pidx[0];
        aeff[b * D_ + d] = (protos[pi * D_ + d] + 0.5f * q[b * D_ + d]) * 0.0625f;
    } else {
        // compact valid (b,t) tile list
        int nT = 0;
        if (tid < B_) nT = min(64, (lengths[tid] + TILE_M - 1) / TILE_M);
        int pre = 0, tot = 0;
#pragma unroll
        for (int j = 0; j < B_; ++j) {
            int v = __shfl(nT, j, 64);
            tot += v;
            if (j < tid) pre += v;
        }
        if (tid < B_) {
            for (int t = 0; t < nT; ++t) tiles[pre + t] = (tid << 16) | t;
        }
        if (tid == 0) tileCnt[0] = tot;
    }
}

// ---------------------------------------------------------------------------
// main: compacted tiles; A register-direct; B LDS double-buffered.
// 4 waves: wave wv -> (rg=wv>>1, ch=wv&1): rows rg*32+[0,32), cols ch*128+[0,128)
// ---------------------------------------------------------------------------
__global__ __launch_bounds__(256, 2) void main_kernel(
    const float* __restrict__ h, const float* __restrict__ rp, const float* __restrict__ rn,
    const int* __restrict__ lengths, const unsigned short* __restrict__ wsW,
    const float* __restrict__ aeff, const float* __restrict__ bhist,
    float* __restrict__ partials, const int* __restrict__ tiles,
    const int* __restrict__ tileCnt)
{
    const int bid = blockIdx.x;
    if (bid >= tileCnt[0]) return;
    const int ent = tiles[bid];
    const int b   = ent >> 16;
    const int t   = ent & 0xFFFF;
    const int len = lengths[b];
    const int l0  = t * TILE_M;

    __shared__ __align__(16) char Bsm[65536];     // B double buffer 2x32KB
    __shared__ float red[128];                    // [ch][64 rows] logit partials
    __shared__ float pbuf[64];                    // softmax weights
    __shared__ float solds[4 * 128];              // [wv][128] s_o partials

    const int tid  = threadIdx.x;
    const int lane = tid & 63;
    const int wv   = tid >> 6;
    const int rg   = wv >> 1;
    const int ch   = wv & 1;
    const int r16  = lane & 15;
    const int kg   = lane >> 4;

    // A fragment source: lane covers row (rg*32 + m*16 + r16), k-chunk kg*8
    const size_t rowA0 = ((size_t)b * L_ + l0 + rg * 32 + r16) * D_ + kg * 8;

    const f32x4 zero4 = {0.f, 0.f, 0.f, 0.f};
    f32x4 acc[2][8];
#pragma unroll
    for (int m = 0; m < 2; ++m)
#pragma unroll
        for (int n = 0; n < 8; ++n) acc[m][n] = zero4;

    f32x4 pA[2][2][2], pB[2][2][2];   // [m][ks][half] raw f32 prefetch
    bf16x8 frag[2][2];                // current-iter A fragments

    auto stageB = [&](int buf, int tk) {
        const char* bsrc = reinterpret_cast<const char*>(wsW) + tk * 32768;
        char* dst = Bsm + buf * 32768;
#pragma unroll
        for (int i = 0; i < 8; ++i) {
            int off = i * 4096 + wv * 1024;
            gload_lds16(bsrc + off + lane * 16, dst + off);
        }
    };
    auto loadA = [&](int tk) {
        if (tk < 4) {
            const float* p0 = h + rowA0 + tk * 64;
#pragma unroll
            for (int m = 0; m < 2; ++m) {
                const float* p = p0 + m * 16 * D_;
#pragma unroll
                for (int ks = 0; ks < 2; ++ks) {
                    pA[m][ks][0] = *reinterpret_cast<const f32x4*>(p + ks * 32);
                    pA[m][ks][1] = *reinterpret_cast<const f32x4*>(p + ks * 32 + 4);
                }
            }
        } else {
            size_t o0 = rowA0 + (tk - 4) * 64;
#pragma unroll
            for (int m = 0; m < 2; ++m) {
                size_t o = o0 + (size_t)m * 16 * D_;
#pragma unroll
                for (int ks = 0; ks < 2; ++ks) {
                    pA[m][ks][0] = *reinterpret_cast<const f32x4*>(rp + o + ks * 32);
                    pA[m][ks][1] = *reinterpret_cast<const f32x4*>(rp + o + ks * 32 + 4);
                    pB[m][ks][0] = *reinterpret_cast<const f32x4*>(rn + o + ks * 32);
                    pB[m][ks][1] = *reinterpret_cast<const f32x4*>(rn + o + ks * 32 + 4);
                }
            }
        }
    };
    auto cvtA = [&](int tk) {
#pragma unroll
        for (int m = 0; m < 2; ++m)
#pragma unroll
            for (int ks = 0; ks < 2; ++ks) {
                f32x4 v0, v1;
                if (tk < 4) { v0 = pA[m][ks][0]; v1 = pA[m][ks][1]; }
                else        { v0 = pA[m][ks][0] - pB[m][ks][0]; v1 = pA[m][ks][1] - pB[m][ks][1]; }
                frag[m][ks] = pack8(v0, v1);
            }
    };
    auto computeT = [&](int buf) {
        const char* Bb = Bsm + buf * 32768;
#pragma unroll
        for (int ks = 0; ks < 2; ++ks) {
#pragma unroll
            for (int nt = 0; nt < 8; ++nt) {
                int d   = ch * 128 + nt * 16 + r16;
                int off = (d * 128 + (ks * 32 + kg * 8) * 2) ^ ((d & 7) << 4);
                bf16x8 bfr = *reinterpret_cast<const bf16x8*>(Bb + off);
                acc[0][nt] = __builtin_amdgcn_mfma_f32_16x16x32_bf16(frag[0][ks], bfr, acc[0][nt], 0, 0, 0);
                acc[1][nt] = __builtin_amdgcn_mfma_f32_16x16x32_bf16(frag[1][ks], bfr, acc[1][nt], 0, 0, 0);
            }
        }
    };

    // prologue
    loadA(0);
    stageB(0, 0);
    cvtA(0);
    __syncthreads();

    int buf = 0;
    for (int tk = 0; tk < KITERS; ++tk) {
        const bool pf = (tk + 1) < KITERS;
        if (pf) { loadA(tk + 1); stageB(buf ^ 1, tk + 1); }
        __builtin_amdgcn_sched_barrier(0);   // pin load issue above compute
        computeT(buf);
        if (pf) cvtA(tk + 1);                // waits A(k+1); overwrites frag for next iter
        __syncthreads();                     // drains B gloads (landed during compute)
        buf ^= 1;
    }

    // ---- epilogue ----------------------------------------------------------
    float av[8], bh[8];
#pragma unroll
    for (int nt = 0; nt < 8; ++nt) {
        int col = ch * 128 + nt * 16 + r16;
        av[nt] = aeff[b * D_ + col];
        bh[nt] = bhist[col];
    }
    float part[2][4];
#pragma unroll
    for (int m = 0; m < 2; ++m)
#pragma unroll
        for (int rgi = 0; rgi < 4; ++rgi) part[m][rgi] = 0.f;
#pragma unroll
    for (int m = 0; m < 2; ++m)
#pragma unroll
        for (int nt = 0; nt < 8; ++nt)
#pragma unroll
            for (int rgi = 0; rgi < 4; ++rgi) {
                float o = fast_tanh(acc[m][nt][rgi] + bh[nt]);
                acc[m][nt][rgi] = o;
                part[m][rgi] += o * av[nt];
            }
    // reduce logit partials over the 16 col-lanes
#pragma unroll
    for (int off = 1; off < 16; off <<= 1)
#pragma unroll
        for (int m = 0; m < 2; ++m)
#pragma unroll
            for (int rgi = 0; rgi < 4; ++rgi)
                part[m][rgi] += __shfl_xor(part[m][rgi], off, 64);
    if (r16 == 0) {
#pragma unroll
        for (int m = 0; m < 2; ++m)
#pragma unroll
            for (int rgi = 0; rgi < 4; ++rgi)
                red[ch * 64 + rg * 32 + m * 16 + kg * 4 + rgi] = part[m][rgi];
    }
    __syncthreads();

    float* pout = partials + (size_t)(b * 64 + t) * PSTRIDE;
    if (tid < 64) {
        int row = tid;
        float lg = red[row] + red[64 + row];
        bool valid = (l0 + row) < len;
        float mv = valid ? lg : -3.0e38f;
#pragma unroll
        for (int off = 1; off < 64; off <<= 1)
            mv = fmaxf(mv, __shfl_xor(mv, off, 64));
        float p = valid ? __expf(lg - mv) : 0.f;
        float sa = p;
#pragma unroll
        for (int off = 1; off < 64; off <<= 1)
            sa += __shfl_xor(sa, off, 64);
        pbuf[row] = p;
        if (tid == 0) { pout[0] = mv; pout[1] = sa; }
    }
    __syncthreads();

    // s_o partial per wave
    float so[8];
#pragma unroll
    for (int nt = 0; nt < 8; ++nt) so[nt] = 0.f;
#pragma unroll
    for (int m = 0; m < 2; ++m)
#pragma unroll
        for (int rgi = 0; rgi < 4; ++rgi) {
            float p = pbuf[rg * 32 + m * 16 + kg * 4 + rgi];
#pragma unroll
            for (int nt = 0; nt < 8; ++nt)
                so[nt] += p * acc[m][nt][rgi];
        }
#pragma unroll
    for (int nt = 0; nt < 8; ++nt) {
        so[nt] += __shfl_xor(so[nt], 16, 64);
        so[nt] += __shfl_xor(so[nt], 32, 64);
    }
    if (lane < 16) {
#pragma unroll
        for (int nt = 0; nt < 8; ++nt)
            solds[wv * 128 + nt * 16 + lane] = so[nt];
    }
    __syncthreads();
    {
        int col = tid;
        int c2  = col >> 7, cl = col & 127;
        pout[2 + col] = solds[c2 * 128 + cl] + solds[(2 + c2) * 128 + cl];
    }
}

// ---------------------------------------------------------------------------
// sq_kernel: per batch combine tile partials -> sq[b][256]
// ---------------------------------------------------------------------------
__global__ __launch_bounds__(256) void sq_kernel(
    const float* __restrict__ partials, const int* __restrict__ lengths,
    float* __restrict__ sqout)
{
    const int b   = blockIdx.x;
    const int tid = threadIdx.x;
    const int len = lengths[b];
    const int nT  = min(64, (len + TILE_M - 1) / TILE_M);

    __shared__ float mArr[64];
    __shared__ float sAArr[64];

    const float* pbase = partials + (size_t)b * 64 * PSTRIDE;
    if (tid < nT) {
        mArr[tid]  = pbase[(size_t)tid * PSTRIDE];
        sAArr[tid] = pbase[(size_t)tid * PSTRIDE + 1];
    }
    __syncthreads();

    float M = -3.0e38f;
    for (int t = 0; t < nT; ++t) M = fmaxf(M, mArr[t]);
    float den = 0.f, num = 0.f;
    for (int t = 0; t < nT; ++t) {
        float f = __expf(mArr[t] - M);
        den += f * sAArr[t];
        num += f * pbase[(size_t)t * PSTRIDE + 2 + tid];
    }
    sqout[b * D_ + tid] = num / den;
}

// ---------------------------------------------------------------------------
// z_kernel: 256 blocks, block r computes z[b][r] for all 16 b
// ---------------------------------------------------------------------------
__global__ __launch_bounds__(256) void z_kernel(
    const float* __restrict__ q, const float* __restrict__ sq,
    const float* __restrict__ protos, const int* __restrict__ pidx,
    const float* __restrict__ Wq_w, const float* __restrict__ Wq_b,
    const float* __restrict__ Ws_w, const float* __restrict__ Ws_b,
    float* __restrict__ zout)
{
    const int r   = blockIdx.x;
    const int tid = threadIdx.x;
    const int bb  = tid >> 4;       // batch
    const int c   = tid & 15;       // 16-elem chunk
    const float4* wq = reinterpret_cast<const float4*>(Wq_w + (size_t)r * D_) + c * 4;
    const float4* ws = reinterpret_cast<const float4*>(Ws_w + (size_t)r * D_) + c * 4;
    const float4* qv = reinterpret_cast<const float4*>(q  + bb * D_) + c * 4;
    const float4* sv = reinterpret_cast<const float4*>(sq + bb * D_) + c * 4;
    float a = 0.f;
#pragma unroll
    for (int i = 0; i < 4; ++i) {
        float4 w1 = wq[i], w2 = ws[i], v1 = qv[i], v2 = sv[i];
        a += w1.x * v1.x + w1.y * v1.y + w1.z * v1.z + w1.w * v1.w;
        a += w2.x * v2.x + w2.y * v2.y + w2.z * v2.z + w2.w * v2.w;
    }
#pragma unroll
    for (int off = 1; off < 16; off <<= 1) a += __shfl_xor(a, off, 64);
    if (c == 0) {
        int pi = pidx[0];
        zout[bb * D_ + r] = protos[pi * D_ + r] + Wq_b[r] + Ws_b[r] + a;
    }
}

// ---------------------------------------------------------------------------
// final: per batch delta = z.(rpos-rneg); softplus; mean via atomicAdd
// ---------------------------------------------------------------------------
__global__ __launch_bounds__(256) void final_kernel(
    const float* __restrict__ zbuf,
    const float* __restrict__ rpos, const float* __restrict__ rneg,
    float* __restrict__ out)
{
    const int b   = blockIdx.x;
    const int tid = threadIdx.x;
    const int lane = tid & 63;
    const int wv   = tid >> 6;
    __shared__ float wsum[4];
    float v = zbuf[b * D_ + tid] * (rpos[b * D_ + tid] - rneg[b * D_ + tid]);
#pragma unroll
    for (int off = 1; off < 64; off <<= 1) v += __shfl_xor(v, off, 64);
    if (lane == 0) wsum[wv] = v;
    __syncthreads();
    if (tid == 0) {
        float delta = wsum[0] + wsum[1] + wsum[2] + wsum[3];
        float x = -delta;
        float sp = fmaxf(x, 0.f) + log1pf(__expf(-fabsf(x)));
        atomicAdd(out, sp * (1.0f / (float)B_));
    }
}

// ---------------------------------------------------------------------------
extern "C" void kernel_launch(void* const* d_in, const int* in_sizes, int n_in,
                              void* d_out, int out_size, void* d_ws, size_t ws_size,
                              hipStream_t stream) {
    const float* q       = (const float*)d_in[0];
    const float* r_pos   = (const float*)d_in[1];
    const float* r_neg   = (const float*)d_in[2];
    const float* h       = (const float*)d_in[3];
    const float* rp      = (const float*)d_in[4];
    const float* rn      = (const float*)d_in[5];
    const int*   lengths = (const int*)d_in[6];
    const int*   pidx    = (const int*)d_in[7];
    const float* protos  = (const float*)d_in[8];
    const float* Wh_w    = (const float*)d_in[9];
    const float* Wh_b    = (const float*)d_in[10];
    const float* Wq_w    = (const float*)d_in[11];
    const float* Wq_b    = (const float*)d_in[12];
    const float* Ws_w    = (const float*)d_in[13];
    const float* Ws_b    = (const float*)d_in[14];
    float* out = (float*)d_out;

    char* ws = (char*)d_ws;
    unsigned short* wsW = (unsigned short*)ws;          // 256 KB pre-swizzled bf16 W
    float* aeff     = (float*)(ws + 262144);            // 16 KB
    float* partials = (float*)(ws + 278528);            // 16*64*264*4 = 1081344 B
    int*   tiles    = (int*)(ws + 1359872);             // 4 KB
    int*   tileCnt  = (int*)(ws + 1363968);             // 4 B
    float* sqws     = (float*)ws;                       // alias wsW (dead after main)
    float* zbuf     = (float*)(ws + 16384);             // alias wsW+16KB

    hipMemsetAsync(out, 0, sizeof(float), stream);
    prep_kernel<<<dim3(273), dim3(256), 0, stream>>>(Wh_w, protos, q, pidx, lengths,
                                                     wsW, aeff, tiles, tileCnt);
    main_kernel<<<dim3(B_ * 64), dim3(256), 0, stream>>>(h, rp, rn, lengths, wsW, aeff, Wh_b,
                                                         partials, tiles, tileCnt);
    sq_kernel<<<dim3(B_), dim3(256), 0, stream>>>(partials, lengths, sqws);
    z_kernel<<<dim3(256), dim3(256), 0, stream>>>(q, sqws, protos, pidx,
                                                  Wq_w, Wq_b, Ws_w, Ws_b, zbuf);
    final_kernel<<<dim3(B_), dim3(256), 0, stream>>>(zbuf, r_pos, r_neg, out);
}